// Round 2
// baseline (166.341 us; speedup 1.0000x reference)
//
#include <hip/hip_runtime.h>
#include <math.h>

#define IMG_W 3840
#define IMG_H 2160
#define OUTW  60        // output columns per wave strip (64 lanes - 4 halo)
#define R     20        // output rows per strip (2160 = 108 * 20, exact)
#define GROWS (R + 4)   // 24 gray rows per strip

// idx -> dx [1,1,0,-1,-1,-1,0,1], dy [0,1,1,1,0,-1,-1,-1], packed as (d+1) 2-bit fields
#define DXPACK 0x901A
#define DYPACK 0x1A9

// Sector boundary slopes in the module's scaled-degree space (RAD2DEG = 180/3.14159)
#define T1_SLOPE 0.41421317376456f
#define T2_SLOPE 2.41420676743300f
#define SECT_EPS 3.0e-5f

__device__ __noinline__ int slow_sector(float sx, float sy) {
#pragma clang fp contract(off)
    const float RADF = (float)(180.0 / 3.14159);
    float t = atan2f(sy, sx);
    float wv = ((t * RADF) + 180.0f) / 45.0f;   // exact f32 chain as reference
    float ori = rintf(wv);                      // round-half-even == np.round
    float fr = fabsf(wv - ori);
    if (fr > 0.4995f) {
        // near a rounding tie: redo atan2 in double -> correctly-rounded f32
        double td = atan2((double)sy, (double)sx);
        float t2 = (float)td;
        wv = ((t2 * RADF) + 180.0f) / 45.0f;
        ori = rintf(wv);
    }
    return ((int)ori) & 7;
}

// ---- pipeline stage macros: ALL array indices are literal constants after
//      manual unroll-by-4 (rule #20: no runtime-indexed register arrays) ----

// issue 3 channel loads of gray row (kk) into buffer slot cj (clamped addr)
#define LOADROW(kk, cj)                                                        \
    {                                                                          \
        const int y_  = Y0 - 2 + (kk);                                         \
        const int yc_ = min(max(y_, 0), IMG_H - 1);                            \
        const int o_  = yc_ * IMG_W + xc;                                      \
        c0[(cj)] = img[o_];                                                    \
        c1[(cj)] = im1[o_];                                                    \
        c2[(cj)] = im2[o_];                                                    \
    }

// consume buffer slot j3 (= (kk)&3): gray value + neighbor shuffles
#define GRAY(kk, j3)                                                           \
    {                                                                          \
        const int  y_   = Y0 - 2 + (kk);                                       \
        const bool yok_ = (unsigned)y_ < (unsigned)IMG_H;                      \
        float t_  = ((c0[(j3)] + c1[(j3)]) + c2[(j3)]) / 3.0f;                 \
        float gv_ = (xok && yok_) ? t_ : 0.0f;                                 \
        g[(j3)]  = gv_;                                                        \
        gl[(j3)] = __shfl_up(gv_, 1);                                          \
        gr[(j3)] = __shfl_down(gv_, 1);                                        \
    }

// mag row from gray rows kk-2,kk-1,kk; ds_write into circular slot; optional NMS
#define MAGROW(kk, j3, DONMS)                                                  \
    {                                                                          \
        const int i0_ = ((j3) + 2) & 3, i1_ = ((j3) + 3) & 3, i2_ = (j3);      \
        float a00 = gl[i0_], a01 = g[i0_], a02 = gr[i0_];                      \
        float a10 = gl[i1_],               a12 = gr[i1_];                      \
        float a20 = gl[i2_], a21 = g[i2_], a22 = gr[i2_];                      \
        float sx = a00;                      /* exact R4 tap order */          \
        sx = sx - a02;                                                         \
        sx = sx + 2.0f * a10;                                                  \
        sx = sx - 2.0f * a12;                                                  \
        sx = sx + a20;                                                         \
        sx = sx - a22;                                                         \
        float sy = a00;                                                        \
        sy = sy + 2.0f * a01;                                                  \
        sy = sy + a02;                                                         \
        sy = sy - a20;                                                         \
        sy = sy - 2.0f * a21;                                                  \
        sy = sy - a22;                                                         \
        float magv = sqrtf(sx * sx + sy * sy);                                 \
        float ax = fabsf(sx), ay = fabsf(sy);                                  \
        float d1 = fmaf(-T1_SLOPE, ax, ay);                                    \
        float d2 = fmaf(-T2_SLOPE, ax, ay);                                    \
        float sA = ax + ay;                                                    \
        int dxo, dyo;                                                          \
        if (__builtin_expect(fabsf(d1) < SECT_EPS * sA ||                      \
                             fabsf(d2) < SECT_EPS * sA, 0)) {                  \
            int idx = slow_sector(sx, sy);                                     \
            dxo = ((DXPACK >> (2 * idx)) & 3) - 1;                             \
            dyo = ((DYPACK >> (2 * idx)) & 3) - 1;                             \
        } else {                                                               \
            dxo = (d2 > 0.0f) ? 0 : ((sx > 0.0f) ? -1 : 1);                    \
            dyo = (d1 < 0.0f) ? 0 : ((sy > 0.0f) ? -1 : 1);                    \
        }                                                                      \
        const bool vok_ = xmok && ((unsigned)(Y0 - 3 + (kk)) < (unsigned)IMG_H); \
        float mag_  = vok_ ? magv : 0.0f;                                      \
        int   offv_ = vok_ ? (dyo * 64 + dxo) : 0;                             \
        B[(((j3) + 2) & 3) * 64 + lane] = mag_;   /* circular slot (kk-2)&3 */ \
        if (DONMS) {                                                           \
            /* NMS for mag written last iter (lag 1): slot (kk-3)&3 = (j3+1)&3.\
               Same-wave DS ops are in-order -> no barrier. Circular wrap via  \
               &255 is exact while 0 <= lane+dx <= 63 (true for used lanes). */\
            const int rp_  = (((j3) + 1) & 3) * 64;                            \
            const int ipp_ = (rp_ + lane + off_p) & 255;                       \
            const int ipn_ = (rp_ + lane - off_p) & 255;                       \
            float mp_ = B[ipp_];                                               \
            float mn_ = B[ipn_];                                               \
            float res_ = (fminf(mc_p - mp_, mc_p - mn_) > 0.0f &&              \
                          mc_p >= 0.2f) ? 1.0f : 0.0f;                         \
            if (xoutok)                                                        \
                out[(size_t)(Y0 + (kk) - 4) * IMG_W + x] = res_;               \
        }                                                                      \
        mc_p  = mag_;                                                          \
        off_p = offv_;                                                         \
    }

__global__ __launch_bounds__(256, 4) void canny_like_kernel(const float* __restrict__ img,
                                                            float* __restrict__ out) {
#pragma clang fp contract(off)
    // per-wave 4-row circular mag buffer: 4 KB/block, no barriers anywhere
    __shared__ float lds_m[4][4][64];

    const int lane = threadIdx.x;                // 0..63
    const int w    = threadIdx.y;                // wave id in block, 0..3
    const int X0   = (blockIdx.x * 4 + w) * OUTW;
    const int Y0   = blockIdx.y * R;
    const int x    = X0 - 2 + lane;              // gray column owned by this lane
    const bool xok    = (unsigned)x < (unsigned)IMG_W;
    const int  xc     = min(max(x, 0), IMG_W - 1);       // clamped (safe addr, value masked)
    const bool xmok   = (lane >= 1) && (lane <= 62) && xok;   // mag-valid lanes
    const bool xoutok = (lane >= 2) && (lane <= 61);          // output lanes

    const float* im1 = img + (size_t)IMG_W * IMG_H;
    const float* im2 = img + 2 * (size_t)IMG_W * IMG_H;

    float* const B = &lds_m[w][0][0];            // wave-private 256-float window

    // pipeline state: 4-slot channel double-buffer + 4-slot rolling gray window.
    // Indices are ALWAYS literals -> registers, never scratch.
    float c0[4], c1[4], c2[4];
    float g[4], gl[4], gr[4];
    float mc_p  = 0.0f;                          // mag of pending NMS row (lag 1)
    int   off_p = 0;                             // its flat NMS offset (lag 1)

    // ---- prologue: prime 3-deep load pipeline, peel rows 0..3 ----
    LOADROW(0, 0)
    LOADROW(1, 1)
    LOADROW(2, 2)
    GRAY(0, 0)  LOADROW(3, 3)
    GRAY(1, 1)  LOADROW(4, 0)
    GRAY(2, 2)  LOADROW(5, 1)  MAGROW(2, 2, 0)
    GRAY(3, 3)  LOADROW(6, 2)  MAGROW(3, 3, 0)

    // ---- main loop: rows 4..23, manual unroll-by-4 (kb % 4 == 0 invariant).
    //      Keep it a REAL loop: tiny I$ footprint, 5 trips. ----
#pragma clang loop unroll(disable)
    for (int kb = 4; kb < GROWS; kb += 4) {
        {   const int k_ = kb + 0;
            LOADROW(k_ + 3, 3)                   // prefetch row k+3 (harmless clamp past end)
            GRAY(k_, 0)
            MAGROW(k_, 0, 1)
        }
        {   const int k_ = kb + 1;
            LOADROW(k_ + 3, 0)
            GRAY(k_, 1)
            MAGROW(k_, 1, 1)
        }
        {   const int k_ = kb + 2;
            LOADROW(k_ + 3, 1)
            GRAY(k_, 2)
            MAGROW(k_, 2, 1)
        }
        {   const int k_ = kb + 3;
            LOADROW(k_ + 3, 2)
            GRAY(k_, 3)
            MAGROW(k_, 3, 1)
        }
    }
}

extern "C" void kernel_launch(void* const* d_in, const int* in_sizes, int n_in,
                              void* d_out, int out_size, void* d_ws, size_t ws_size,
                              hipStream_t stream) {
    const float* img = (const float*)d_in[0];
    float* out = (float*)d_out;
    // 64 x-strips (60 cols each, 64*60 = 3840 exact) x 108 y-strips (20 rows, exact)
    dim3 grid(64 / 4, IMG_H / R);                // (16, 108) = 1728 blocks, 4 waves each
    dim3 block(64, 4);
    canny_like_kernel<<<grid, block, 0, stream>>>(img, out);
}

// Round 3
// 163.350 us; speedup vs baseline: 1.0183x; 1.0183x over previous
//
#include <hip/hip_runtime.h>
#include <math.h>

#define IMG_W 3840
#define IMG_H 2160
#define OUTW  60        // output columns per wave strip (64 lanes - 4 halo)
#define R     12        // output rows per strip (2160 = 180 * 12, exact)
#define GROWS (R + 4)   // 16 gray rows per strip

// idx -> dx [1,1,0,-1,-1,-1,0,1], dy [0,1,1,1,0,-1,-1,-1], packed as (d+1) 2-bit fields
#define DXPACK 0x901A
#define DYPACK 0x1A9

// Sector boundary slopes in the module's scaled-degree space (RAD2DEG = 180/3.14159)
#define T1_SLOPE 0.41421317376456f
#define T2_SLOPE 2.41420676743300f
#define SECT_EPS 3.0e-5f

__device__ __noinline__ int slow_sector(float sx, float sy) {
#pragma clang fp contract(off)
    const float RADF = (float)(180.0 / 3.14159);
    float t = atan2f(sy, sx);
    float wv = ((t * RADF) + 180.0f) / 45.0f;   // exact f32 chain as reference
    float ori = rintf(wv);                      // round-half-even == np.round
    float fr = fabsf(wv - ori);
    if (fr > 0.4995f) {
        // near a rounding tie: redo atan2 in double -> correctly-rounded f32
        double td = atan2((double)sy, (double)sx);
        float t2 = (float)td;
        wv = ((t2 * RADF) + 180.0f) / 45.0f;
        ori = rintf(wv);
    }
    return ((int)ori) & 7;
}

// ---- pipeline stage macros: ALL array indices are literal constants in the
//      fully straight-line schedule (rule #20: no runtime-indexed reg arrays) ----

// issue 3 channel loads of gray row (kk) into 8-slot buffer slot cj = kk&7
#define LOADROW(kk, cj)                                                        \
    {                                                                          \
        const int y_  = Y0 - 2 + (kk);                                         \
        const int yc_ = min(max(y_, 0), IMG_H - 1);                            \
        const int o_  = yc_ * IMG_W + xc;                                      \
        c0[(cj)] = img[o_];                                                    \
        c1[(cj)] = im1[o_];                                                    \
        c2[(cj)] = im2[o_];                                                    \
    }

// consume c-slot cj (= kk&7): gray value + neighbor shuffles into window j3 (= kk&3)
#define GRAY(kk, cj, j3)                                                       \
    {                                                                          \
        const int  y_   = Y0 - 2 + (kk);                                       \
        const bool yok_ = (unsigned)y_ < (unsigned)IMG_H;                      \
        float t_  = ((c0[(cj)] + c1[(cj)]) + c2[(cj)]) / 3.0f;                 \
        float gv_ = (xok && yok_) ? t_ : 0.0f;                                 \
        g[(j3)]  = gv_;                                                        \
        gl[(j3)] = __shfl_up(gv_, 1);                                          \
        gr[(j3)] = __shfl_down(gv_, 1);                                        \
    }

// mag row from gray rows kk-2,kk-1,kk (image row Y0-3+kk); LDS slot (kk-2)&3; lag-1 NMS
#define MAGROW(kk, j3, DONMS)                                                  \
    {                                                                          \
        const int i0_ = ((j3) + 2) & 3, i1_ = ((j3) + 3) & 3, i2_ = (j3);      \
        float a00 = gl[i0_], a01 = g[i0_], a02 = gr[i0_];                      \
        float a10 = gl[i1_],               a12 = gr[i1_];                      \
        float a20 = gl[i2_], a21 = g[i2_], a22 = gr[i2_];                      \
        float sx = a00;                      /* exact R4 tap order */          \
        sx = sx - a02;                                                         \
        sx = sx + 2.0f * a10;                                                  \
        sx = sx - 2.0f * a12;                                                  \
        sx = sx + a20;                                                         \
        sx = sx - a22;                                                         \
        float sy = a00;                                                        \
        sy = sy + 2.0f * a01;                                                  \
        sy = sy + a02;                                                         \
        sy = sy - a20;                                                         \
        sy = sy - 2.0f * a21;                                                  \
        sy = sy - a22;                                                         \
        float magv = sqrtf(sx * sx + sy * sy);                                 \
        float ax = fabsf(sx), ay = fabsf(sy);                                  \
        float d1 = fmaf(-T1_SLOPE, ax, ay);                                    \
        float d2 = fmaf(-T2_SLOPE, ax, ay);                                    \
        float sA = ax + ay;                                                    \
        int dxo, dyo;                                                          \
        if (__builtin_expect(fabsf(d1) < SECT_EPS * sA ||                      \
                             fabsf(d2) < SECT_EPS * sA, 0)) {                  \
            int idx = slow_sector(sx, sy);                                     \
            dxo = ((DXPACK >> (2 * idx)) & 3) - 1;                             \
            dyo = ((DYPACK >> (2 * idx)) & 3) - 1;                             \
        } else {                                                               \
            dxo = (d2 > 0.0f) ? 0 : ((sx > 0.0f) ? -1 : 1);                    \
            dyo = (d1 < 0.0f) ? 0 : ((sy > 0.0f) ? -1 : 1);                    \
        }                                                                      \
        const bool vok_ = xmok && ((unsigned)(Y0 - 3 + (kk)) < (unsigned)IMG_H); \
        float mag_  = vok_ ? magv : 0.0f;                                      \
        int   offv_ = vok_ ? (dyo * 64 + dxo) : 0;                             \
        B[(((j3) + 2) & 3) * 64 + lane] = mag_;   /* circular slot (kk-2)&3 */ \
        if (DONMS) {                                                           \
            /* NMS for mag written last MAGROW (lag 1): slot (kk-3)&3.         \
               Same-wave DS ops are in-order -> no barrier. Circular wrap via  \
               &255 is exact while 0 <= lane+dx <= 63 (true for used lanes). */\
            const int rp_  = (((j3) + 1) & 3) * 64;                            \
            const int ipp_ = (rp_ + lane + off_p) & 255;                       \
            const int ipn_ = (rp_ + lane - off_p) & 255;                       \
            float mp_ = B[ipp_];                                               \
            float mn_ = B[ipn_];                                               \
            float res_ = (fminf(mc_p - mp_, mc_p - mn_) > 0.0f &&              \
                          mc_p >= 0.2f) ? 1.0f : 0.0f;                         \
            if (xoutok)                                                        \
                out[(size_t)(Y0 + (kk) - 4) * IMG_W + x] = res_;               \
        }                                                                      \
        mc_p  = mag_;                                                          \
        off_p = offv_;                                                         \
    }

__global__ __launch_bounds__(256, 4) void canny_like_kernel(const float* __restrict__ img,
                                                            float* __restrict__ out) {
#pragma clang fp contract(off)
    // per-wave 4-row circular mag buffer: 4 KB/block, no barriers anywhere
    __shared__ float lds_m[4][4][64];

    const int lane = threadIdx.x;                // 0..63
    const int w    = threadIdx.y;                // wave id in block, 0..3
    const int X0   = (blockIdx.x * 4 + w) * OUTW;
    const int Y0   = blockIdx.y * R;
    const int x    = X0 - 2 + lane;              // gray column owned by this lane
    const bool xok    = (unsigned)x < (unsigned)IMG_W;
    const int  xc     = min(max(x, 0), IMG_W - 1);       // clamped (safe addr, value masked)
    const bool xmok   = (lane >= 1) && (lane <= 62) && xok;   // mag-valid lanes
    const bool xoutok = (lane >= 2) && (lane <= 61);          // output lanes

    const float* im1 = img + (size_t)IMG_W * IMG_H;
    const float* im2 = img + 2 * (size_t)IMG_W * IMG_H;

    float* const B = &lds_m[w][0][0];            // wave-private 256-float window

    // pipeline state: 8-slot channel buffers (24 loads in flight, ~2400 cy of
    // issue cover >> 900 cy HBM latency) + 4-slot rolling gray window.
    // Indices are ALWAYS literals -> registers, never scratch.
    float c0[8], c1[8], c2[8];
    float g[4], gl[4], gr[4];
    float mc_p  = 0.0f;                          // mag of pending NMS row (lag 1)
    int   off_p = 0;                             // its flat NMS offset (lag 1)

    // ---- prologue: prime 8-deep load pipeline (rows 0..7 of 16) ----
    LOADROW(0, 0)  LOADROW(1, 1)  LOADROW(2, 2)  LOADROW(3, 3)
    LOADROW(4, 4)  LOADROW(5, 5)  LOADROW(6, 6)  LOADROW(7, 7)

    // ---- phase A: consume row k, immediately refill its slot with row k+8.
    //      Consume-before-reload (WAR on c[k&7]) pins the 8-deep steady state. ----
    GRAY(0, 0, 0)  LOADROW( 8, 0)
    GRAY(1, 1, 1)  LOADROW( 9, 1)
    GRAY(2, 2, 2)  LOADROW(10, 2)  MAGROW(2, 2, 0)
    GRAY(3, 3, 3)  LOADROW(11, 3)  MAGROW(3, 3, 0)
    GRAY(4, 4, 0)  LOADROW(12, 4)  MAGROW(4, 0, 1)
    GRAY(5, 5, 1)  LOADROW(13, 5)  MAGROW(5, 1, 1)
    GRAY(6, 6, 2)  LOADROW(14, 6)  MAGROW(6, 2, 1)
    GRAY(7, 7, 3)  LOADROW(15, 7)  MAGROW(7, 3, 1)

    // ---- phase B: drain (rows 8..15, all loads already in flight) ----
    GRAY( 8, 0, 0)  MAGROW( 8, 0, 1)
    GRAY( 9, 1, 1)  MAGROW( 9, 1, 1)
    GRAY(10, 2, 2)  MAGROW(10, 2, 1)
    GRAY(11, 3, 3)  MAGROW(11, 3, 1)
    GRAY(12, 4, 0)  MAGROW(12, 0, 1)
    GRAY(13, 5, 1)  MAGROW(13, 1, 1)
    GRAY(14, 6, 2)  MAGROW(14, 2, 1)
    GRAY(15, 7, 3)  MAGROW(15, 3, 1)
}

extern "C" void kernel_launch(void* const* d_in, const int* in_sizes, int n_in,
                              void* d_out, int out_size, void* d_ws, size_t ws_size,
                              hipStream_t stream) {
    const float* img = (const float*)d_in[0];
    float* out = (float*)d_out;
    // 64 x-strips (60 cols each, 64*60 = 3840 exact) x 180 y-strips (12 rows, exact)
    dim3 grid(64 / 4, IMG_H / R);                // (16, 180) = 2880 blocks, 4 waves each
    dim3 block(64, 4);
    canny_like_kernel<<<grid, block, 0, stream>>>(img, out);
}